// Round 1
// baseline (1773.189 us; speedup 1.0000x reference)
//
#include <hip/hip_runtime.h>
#include <cstddef>

// DifferentiableRollout: x_{t+1} = x + DT * ( tanh([x,u]@W1 + b1) @ W2 + b2 )
// B=1024, T=200, SD=64, CD=32, H=512.  Output states [B, T+1, SD] fp32.
//
// Round 0: correctness-first fp32 kernel.
//  - Each batch row is independent -> persistent blocks, 4 rows/block, 256 blocks.
//  - State xc kept transposed in LDS ([96][4]) so GEMM1 reads it as one float4
//    broadcast per k.  h kept row-major [4][512] for broadcast float4 reads in
//    GEMM2.  Weights streamed from global (L2-resident, 327 KB) each step.
//  - 512 threads (8 waves -> 2/SIMD) for L2 latency hiding; GEMM2 uses the
//    first 256 threads (one per (row, s) output).

constexpr int B_  = 1024;
constexpr int T_  = 200;
constexpr int SD_ = 64;
constexpr int CD_ = 32;
constexpr int H_  = 512;
constexpr int KD_ = SD_ + CD_;   // 96
constexpr float DT_ = 0.1f;
constexpr int ROWS_ = 4;         // rows per block
constexpr int THREADS_ = 512;

__global__ __launch_bounds__(THREADS_) void rollout_fp32_kernel(
    const float* __restrict__ x0,     // [B, SD]
    const float* __restrict__ ctrl,   // [B, T, CD]
    const float* __restrict__ W1,     // [KD, H]
    const float* __restrict__ b1,     // [H]
    const float* __restrict__ W2,     // [H, SD]
    const float* __restrict__ b2,     // [SD]
    float* __restrict__ out)          // [B, T+1, SD]
{
    __shared__ float xcT[KD_][ROWS_];   // transposed state+control
    __shared__ float hbuf[ROWS_][H_];   // activations

    const int tid = threadIdx.x;
    const int r0  = blockIdx.x * ROWS_;

    // ---- init: load x0 rows into xcT, write states[:, 0, :] ----
    if (tid < ROWS_ * SD_) {
        const int r = tid >> 6;          // 0..3
        const int s = tid & 63;          // 0..63
        const float v = x0[(size_t)(r0 + r) * SD_ + s];
        xcT[s][r] = v;
        out[(size_t)(r0 + r) * (T_ + 1) * SD_ + s] = v;
    }

    // GEMM1 per-thread constants: one hidden column j per thread
    const int j = tid;                   // 0..511
    const float bj = b1[j];

    // GEMM2 per-thread constants (threads < 256)
    const int r2 = (tid >> 6) & 3;       // row 0..3 for tid<256
    const int s2 = tid & 63;
    const float bs = b2[s2];

    __syncthreads();

    for (int t = 0; t < T_; ++t) {
        // ---- load this step's controls into xcT[64..96][r] ----
        if (tid < ROWS_ * CD_) {         // 128 threads
            const int rr = tid >> 5;     // 0..3
            const int c  = tid & 31;     // 0..31
            xcT[SD_ + c][rr] =
                ctrl[(size_t)(r0 + rr) * T_ * CD_ + (size_t)t * CD_ + c];
        }
        __syncthreads();

        // ---- GEMM1: h[r][j] = tanh(b1[j] + sum_k xc[r][k] * W1[k][j]) ----
        float a0 = bj, a1 = bj, a2 = bj, a3 = bj;
        #pragma unroll 8
        for (int k = 0; k < KD_; ++k) {
            const float w = W1[(size_t)k * H_ + j];      // coalesced, L2-hot
            const float4 xv = *(const float4*)&xcT[k][0]; // LDS broadcast
            a0 += xv.x * w;
            a1 += xv.y * w;
            a2 += xv.z * w;
            a3 += xv.w * w;
        }
        hbuf[0][j] = tanhf(a0);
        hbuf[1][j] = tanhf(a1);
        hbuf[2][j] = tanhf(a2);
        hbuf[3][j] = tanhf(a3);
        __syncthreads();

        // ---- GEMM2 + state update: first 256 threads, one (r,s) each ----
        if (tid < ROWS_ * SD_) {
            float acc = 0.f;
            const float* __restrict__ hrow = &hbuf[r2][0];
            #pragma unroll 4
            for (int jj = 0; jj < H_; jj += 4) {
                const float4 hv = *(const float4*)&hrow[jj];  // LDS broadcast
                acc += hv.x * W2[(size_t)(jj + 0) * SD_ + s2];
                acc += hv.y * W2[(size_t)(jj + 1) * SD_ + s2];
                acc += hv.z * W2[(size_t)(jj + 2) * SD_ + s2];
                acc += hv.w * W2[(size_t)(jj + 3) * SD_ + s2];
            }
            const float xnew = xcT[s2][r2] + DT_ * (acc + bs);
            xcT[s2][r2] = xnew;
            out[(size_t)(r0 + r2) * (T_ + 1) * SD_ + (size_t)(t + 1) * SD_ + s2] = xnew;
        }
        // no barrier needed here: next iteration's ctrl writes touch
        // xcT[64..96] which nobody reads between the mid-barrier and the
        // top-of-loop barrier; xcT[s][r] is read/written only by its owner.
    }
}

extern "C" void kernel_launch(void* const* d_in, const int* in_sizes, int n_in,
                              void* d_out, int out_size, void* d_ws, size_t ws_size,
                              hipStream_t stream) {
    const float* x0   = (const float*)d_in[0];
    const float* ctrl = (const float*)d_in[1];
    const float* W1   = (const float*)d_in[2];
    const float* b1   = (const float*)d_in[3];
    const float* W2   = (const float*)d_in[4];
    const float* b2   = (const float*)d_in[5];
    float* out = (float*)d_out;

    dim3 grid(B_ / ROWS_);      // 256 blocks -> 1 per CU
    dim3 block(THREADS_);
    rollout_fp32_kernel<<<grid, block, 0, stream>>>(x0, ctrl, W1, b1, W2, b2, out);
}